// Round 3
// baseline (11280.785 us; speedup 1.0000x reference)
//
#include <hip/hip_runtime.h>

// ---------------------------------------------------------------------------
// 2-layer LSTM (B=2048, T=64, I=128, H=1024) + per-step fc, MI355X/gfx950.
// Round 2 (resubmit; r2 bench was an infra timeout): dependency-split for
// occupancy.
//   Phase A (1040 blk): cell1 gates (x_t,h1_{t-1}) + partial2a = h2_{t-1}@Whh2
//                       (fp32 buf) + fc_{t-1} rider.  ~4 blocks/CU.
//   Phase B (1024 blk): cell2 finish = h1_t@Wih2 + partial + gate epilogue,
//                       64x128 tiles. 4 blocks/CU.
// Both launches use bijective chunked XCD swizzle (T1) with weight-panel-major
// block order for per-XCD L2 reuse.
// ---------------------------------------------------------------------------

typedef _Float16 f16x8 __attribute__((ext_vector_type(8)));
typedef _Float16 f16x4 __attribute__((ext_vector_type(4)));
typedef float    f32x4 __attribute__((ext_vector_type(4)));

#define DEVI __device__ __forceinline__

constexpr int BB = 2048;           // batch
constexpr int TT = 64;             // time steps
constexpr int II = 128;            // input size
constexpr int HH = 1024;           // hidden size
constexpr int BH = BB * HH;        // elements in one [B,H] state

DEVI void gload_lds16(const _Float16* g, _Float16* l) {
  __builtin_amdgcn_global_load_lds(
      (const __attribute__((address_space(1))) void*)g,
      (__attribute__((address_space(3))) void*)l, 16, 0, 0);
}

DEVI float fsig(float x)  { return 1.0f / (1.0f + __expf(-x)); }
DEVI float ftanh(float x) { float e = __expf(2.0f * x); return 1.0f - 2.0f / (e + 1.0f); }

// ---------------------------------------------------------------------------
// GEMM core, tile MT x 128 (MT in {64,128}), K fused from two (ptr,ld) pairs.
// B is [N][K] row-major (weights). GATES=true maps tile col c to weight row
// ((c>>4)&3)*H + n0 + (c>>6)*16 + (c&15)  (gate-interleaved so each lane's
// 4 N-frags are the 4 gates of one hidden unit).
// LDS: panel-major [4][rows][8] halves -> linear staging (global_load_lds) and
// 256B-contiguous per-16-lane ds_read_b128 (conflict-free; verified 0 in r1).
// ---------------------------------------------------------------------------
template<bool GATES, int MT>
DEVI void gemm_core(f32x4 (&acc)[MT / 32][4],
    const _Float16* __restrict__ A0, int lda0,
    const _Float16* __restrict__ A1, int lda1,
    const _Float16* __restrict__ B0, int ldb0,
    const _Float16* __restrict__ B1, int ldb1,
    int ktSplit, int ktTotal, int m0, int n0,
    _Float16* sA0, _Float16* sA1, _Float16* sB0, _Float16* sB1,
    int tid, int wm, int wn, int lr, int lk)
{
  constexpr int AM  = MT / 32;     // A frags per wave
  constexpr int ALD = MT / 64;     // A staging loads per thread (1 or 2)

  const _Float16* aS0[2]; const _Float16* aS1[2];
  const _Float16* bS0[2]; const _Float16* bS1[2];
#pragma unroll
  for (int i = 0; i < ALD; ++i) {
    int idx = i * 256 + tid;
    int p = idx / MT;            // k-panel 0..3
    int r = idx % MT;            // tile m-row
    aS0[i] = A0 + (size_t)(m0 + r) * lda0 + p * 8;
    aS1[i] = A1 + (size_t)(m0 + r) * lda1 + p * 8;
  }
#pragma unroll
  for (int i = 0; i < 2; ++i) {
    int idx = i * 256 + tid;
    int p = idx >> 7;
    int r = idx & 127;           // tile out-col
    int br = GATES ? (((r >> 4) & 3) * HH + n0 + ((r >> 6) << 4) + (r & 15))
                   : (n0 + r);
    bS0[i] = B0 + (size_t)br * ldb0 + p * 8;
    bS1[i] = B1 + (size_t)br * ldb1 + p * 8;
  }

  auto stage = [&](_Float16* tA, _Float16* tB, int kt) {
    bool s0 = kt < ktSplit;
    int ko = (s0 ? kt : kt - ktSplit) * 32;
#pragma unroll
    for (int i = 0; i < ALD; ++i)
      gload_lds16((s0 ? aS0[i] : aS1[i]) + ko, tA + i * 2048 + tid * 8);
#pragma unroll
    for (int i = 0; i < 2; ++i)
      gload_lds16((s0 ? bS0[i] : bS1[i]) + ko, tB + i * 2048 + tid * 8);
  };

  const int aOff = lk * (MT * 8) + (wm * (MT / 2) + lr) * 8;
  const int bOff = lk * 1024 + (wn * 64 + lr) * 8;

  auto compute = [&](const _Float16* tA, const _Float16* tB) {
    f16x8 av[AM], bv[4];
#pragma unroll
    for (int q = 0; q < AM; ++q) av[q] = *(const f16x8*)(tA + aOff + q * 128);
#pragma unroll
    for (int q = 0; q < 4; ++q) bv[q] = *(const f16x8*)(tB + bOff + q * 128);
#pragma unroll
    for (int i = 0; i < AM; ++i)
#pragma unroll
      for (int j = 0; j < 4; ++j)
        acc[i][j] = __builtin_amdgcn_mfma_f32_16x16x32_f16(av[i], bv[j], acc[i][j], 0, 0, 0);
  };

  stage(sA0, sB0, 0);
  __syncthreads();
  for (int kt = 0; kt < ktTotal; kt += 2) {          // ktTotal always even
    if (kt + 1 < ktTotal) stage(sA1, sB1, kt + 1);
    compute(sA0, sB0);
    __syncthreads();
    if (kt + 2 < ktTotal) stage(sA0, sB0, kt + 2);
    compute(sA1, sB1);
    __syncthreads();
  }
}

DEVI int xcd_swizzle(int grid8) {
  // bijective when gridDim % 8 == 0 (all our grids are)
  return ((int)blockIdx.x % 8) * grid8 + (int)blockIdx.x / 8;
}

// ---------------------------------------------------------------------------
// Phase A: [0,nCell1): cell1 tiles; [nCell1,nCell1+nPart): partial2a tiles;
// rest: fc tiles for step t-1 (skipped when yout==nullptr).
// ---------------------------------------------------------------------------
__global__ __launch_bounds__(256)
void phaseA(
    const _Float16* __restrict__ xt,      // x_t, lda = TT*II
    const _Float16* __restrict__ h1r,     // h1_{t-1}
    const _Float16* __restrict__ h2r,     // h2_{t-1}
    const _Float16* __restrict__ wih1h,
    const _Float16* __restrict__ whh1h,
    const _Float16* __restrict__ whh2h,
    const float* __restrict__ b1s,
    float* __restrict__ c1b,
    _Float16* __restrict__ h1w,
    float* __restrict__ h1F32, float* __restrict__ c1F32,
    float* __restrict__ pbuf,             // [B][4H] fp32, gate-interleaved u*4+g
    const _Float16* __restrict__ fcW,
    const float* __restrict__ fcBias,
    float* __restrict__ yout,             // d_out + (t-1)*II, null -> skip
    int nCell1, int nPart, int grid8)
{
  __shared__ __align__(16) _Float16 sA[2][4096];
  __shared__ __align__(16) _Float16 sB[2][4096];

  const int tid  = threadIdx.x;
  const int lane = tid & 63;
  const int wid  = tid >> 6;
  const int wm = wid >> 1, wn = wid & 1;
  const int lr = lane & 15, lk = lane >> 4;

  const int bid = xcd_swizzle(grid8);

  const f32x4 vzero = {0.f, 0.f, 0.f, 0.f};
  f32x4 acc[4][4];
#pragma unroll
  for (int i = 0; i < 4; ++i)
#pragma unroll
    for (int j = 0; j < 4; ++j) acc[i][j] = vzero;

  if (bid < nCell1) {
    // ---------------- cell1: gates = x_t@Wih1^T + h1_{t-1}@Whh1^T ----------
    const int nt = bid >> 4;           // n-panel-major: consecutive share panel
    const int mt = bid & 15;
    const int m0 = mt * 128, u0 = nt * 32;
    gemm_core<true, 128>(acc, xt, TT * II, h1r, HH, wih1h, II, whh1h, HH,
                         4, 36, m0, u0,
                         sA[0], sA[1], sB[0], sB[1], tid, wm, wn, lr, lk);
    const int u = u0 + wn * 16 + lr;
    const float bi = b1s[u];
    const float bf = b1s[HH + u];
    const float bg = b1s[2 * HH + u];
    const float bo = b1s[3 * HH + u];
#pragma unroll
    for (int mf = 0; mf < 4; ++mf)
#pragma unroll
      for (int rg = 0; rg < 4; ++rg) {
        const int m = m0 + wm * 64 + mf * 16 + lk * 4 + rg;
        const size_t off = (size_t)m * HH + u;
        float iv = fsig (acc[mf][0][rg] + bi);
        float fv = fsig (acc[mf][1][rg] + bf);
        float gv = ftanh(acc[mf][2][rg] + bg);
        float ov = fsig (acc[mf][3][rg] + bo);
        float cn = fv * c1b[off] + iv * gv;
        float hn = ov * ftanh(cn);
        c1b[off] = cn;
        h1w[off] = (_Float16)hn;
        if (h1F32) { h1F32[off] = hn; c1F32[off] = cn; }
      }
  } else if (bid < nCell1 + nPart) {
    // ---------------- partial2a = h2_{t-1} @ Whh2^T ------------------------
    const int b  = bid - nCell1;
    const int nt = b >> 4;
    const int mt = b & 15;
    const int m0 = mt * 128, u0 = nt * 32;
    gemm_core<true, 128>(acc, h2r, HH, h2r, HH, whh2h, HH, whh2h, HH,
                         32, 32, m0, u0,
                         sA[0], sA[1], sB[0], sB[1], tid, wm, wn, lr, lk);
    const int u = u0 + wn * 16 + lr;
#pragma unroll
    for (int mf = 0; mf < 4; ++mf)
#pragma unroll
      for (int rg = 0; rg < 4; ++rg) {
        const int m = m0 + wm * 64 + mf * 16 + lk * 4 + rg;
        float4 v = make_float4(acc[mf][0][rg], acc[mf][1][rg],
                               acc[mf][2][rg], acc[mf][3][rg]);
        *(float4*)(pbuf + (size_t)m * (4 * HH) + u * 4) = v;
      }
  } else {
    // ---------------- fc for step t-1 --------------------------------------
    if (yout == nullptr) return;
    const int m0 = (bid - nCell1 - nPart) * 128;
    gemm_core<false, 128>(acc, h2r, HH, h2r, HH, fcW, HH, fcW, HH,
                          32, 32, m0, 0,
                          sA[0], sA[1], sB[0], sB[1], tid, wm, wn, lr, lk);
#pragma unroll
    for (int mf = 0; mf < 4; ++mf)
#pragma unroll
      for (int fn = 0; fn < 4; ++fn) {
        const int col = wn * 64 + fn * 16 + lr;
        const float bb = fcBias[col];
#pragma unroll
        for (int rg = 0; rg < 4; ++rg) {
          const int m = m0 + wm * 64 + mf * 16 + lk * 4 + rg;
          yout[(size_t)m * (TT * II) + col] = acc[mf][fn][rg] + bb;
        }
      }
  }
}

// ---------------------------------------------------------------------------
// Phase B: cell2 finish. 64x128 tiles, grid 1024 (4 blocks/CU).
// gates = h1_t@Wih2^T + pbuf + bias -> activations -> c2, h2.
// ---------------------------------------------------------------------------
__global__ __launch_bounds__(256)
void phaseB(
    const _Float16* __restrict__ h1w,
    const _Float16* __restrict__ wih2h,
    const float* __restrict__ b2s,
    const float* __restrict__ pbuf,
    float* __restrict__ c2b,
    _Float16* __restrict__ h2w,
    float* __restrict__ h2F32, float* __restrict__ c2F32,
    int grid8)
{
  __shared__ __align__(16) _Float16 sA[2][2048];
  __shared__ __align__(16) _Float16 sB[2][4096];

  const int tid  = threadIdx.x;
  const int lane = tid & 63;
  const int wid  = tid >> 6;
  const int wm = wid >> 1, wn = wid & 1;
  const int lr = lane & 15, lk = lane >> 4;

  const int bid = xcd_swizzle(grid8);
  const int nt = bid >> 5;             // 32 n-panels, panel-major
  const int mt = bid & 31;             // 32 m-tiles of 64
  const int m0 = mt * 64, u0 = nt * 32;

  const f32x4 vzero = {0.f, 0.f, 0.f, 0.f};
  f32x4 acc[2][4];
#pragma unroll
  for (int i = 0; i < 2; ++i)
#pragma unroll
    for (int j = 0; j < 4; ++j) acc[i][j] = vzero;

  gemm_core<true, 64>(acc, h1w, HH, h1w, HH, wih2h, HH, wih2h, HH,
                      32, 32, m0, u0,
                      sA[0], sA[1], sB[0], sB[1], tid, wm, wn, lr, lk);

  const int u = u0 + wn * 16 + lr;
  const float bi = b2s[u];
  const float bf = b2s[HH + u];
  const float bg = b2s[2 * HH + u];
  const float bo = b2s[3 * HH + u];
#pragma unroll
  for (int mf = 0; mf < 2; ++mf)
#pragma unroll
    for (int rg = 0; rg < 4; ++rg) {
      const int m = m0 + wm * 32 + mf * 16 + lk * 4 + rg;
      const size_t off = (size_t)m * HH + u;
      float4 pv = *(const float4*)(pbuf + (size_t)m * (4 * HH) + u * 4);
      float iv = fsig (acc[mf][0][rg] + pv.x + bi);
      float fv = fsig (acc[mf][1][rg] + pv.y + bf);
      float gv = ftanh(acc[mf][2][rg] + pv.z + bg);
      float ov = fsig (acc[mf][3][rg] + pv.w + bo);
      float cn = fv * c2b[off] + iv * gv;
      float hn = ov * ftanh(cn);
      c2b[off] = cn;
      h2w[off] = (_Float16)hn;
      if (h2F32) { h2F32[off] = hn; c2F32[off] = cn; }
    }
}

// ---------------------------------------------------------------------------
// prologue helpers
// ---------------------------------------------------------------------------
__global__ void cvt_f32_f16(const float* __restrict__ in,
                            _Float16* __restrict__ out, int n4) {
  int i  = blockIdx.x * blockDim.x + threadIdx.x;
  int st = gridDim.x * blockDim.x;
  for (; i < n4; i += st) {
    float4 v = ((const float4*)in)[i];
    f16x4 h;
    h[0] = (_Float16)v.x; h[1] = (_Float16)v.y;
    h[2] = (_Float16)v.z; h[3] = (_Float16)v.w;
    ((f16x4*)out)[i] = h;
  }
}

__global__ void bias_sum(const float* __restrict__ a, const float* __restrict__ b,
                         float* __restrict__ o, int n) {
  int i = blockIdx.x * blockDim.x + threadIdx.x;
  if (i < n) o[i] = a[i] + b[i];
}

// ---------------------------------------------------------------------------
extern "C" void kernel_launch(void* const* d_in, const int* in_sizes, int n_in,
                              void* d_out, int out_size, void* d_ws, size_t ws_size,
                              hipStream_t stream) {
  const float* x    = (const float*)d_in[0];
  const float* h1_0 = (const float*)d_in[1];
  const float* c1_0 = (const float*)d_in[2];
  const float* h2_0 = (const float*)d_in[3];
  const float* c2_0 = (const float*)d_in[4];
  const float* wih1 = (const float*)d_in[5];
  const float* whh1 = (const float*)d_in[6];
  const float* bih1 = (const float*)d_in[7];
  const float* bhh1 = (const float*)d_in[8];
  const float* wih2 = (const float*)d_in[9];
  const float* whh2 = (const float*)d_in[10];
  const float* bih2 = (const float*)d_in[11];
  const float* bhh2 = (const float*)d_in[12];
  const float* fcw  = (const float*)d_in[13];
  const float* fcb  = (const float*)d_in[14];
  float* out = (float*)d_out;

  // ---- workspace carve-out (~114 MB) ----
  char* p = (char*)d_ws;
  auto take = [&](size_t bytes) -> void* {
    void* r = (void*)p;
    p += (bytes + 511) & ~(size_t)511;
    return r;
  };
  _Float16* xh    = (_Float16*)take((size_t)BB * TT * II * 2);
  _Float16* wih1h = (_Float16*)take((size_t)4096 * 128 * 2);
  _Float16* whh1h = (_Float16*)take((size_t)4096 * 1024 * 2);
  _Float16* wih2h = (_Float16*)take((size_t)4096 * 1024 * 2);
  _Float16* whh2h = (_Float16*)take((size_t)4096 * 1024 * 2);
  _Float16* fcwh  = (_Float16*)take((size_t)128 * 1024 * 2);
  float*    b1s   = (float*)take(4096 * 4);
  float*    b2s   = (float*)take(4096 * 4);
  _Float16* h1p   = (_Float16*)take((size_t)2 * BH * 2);
  _Float16* h2p   = (_Float16*)take((size_t)2 * BH * 2);
  float*    c1b   = (float*)take((size_t)BH * 4);
  float*    c2b   = (float*)take((size_t)BH * 4);
  float*    pbuf  = (float*)take((size_t)BB * 4 * HH * 4);   // 32 MB

  cvt_f32_f16<<<1024, 256, 0, stream>>>(x,    xh,    BB * TT * II / 4);
  cvt_f32_f16<<<256,  256, 0, stream>>>(wih1, wih1h, 4096 * 128 / 4);
  cvt_f32_f16<<<1024, 256, 0, stream>>>(whh1, whh1h, 4096 * 1024 / 4);
  cvt_f32_f16<<<1024, 256, 0, stream>>>(wih2, wih2h, 4096 * 1024 / 4);
  cvt_f32_f16<<<1024, 256, 0, stream>>>(whh2, whh2h, 4096 * 1024 / 4);
  cvt_f32_f16<<<128,  256, 0, stream>>>(fcw,  fcwh,  128 * 1024 / 4);
  cvt_f32_f16<<<512,  256, 0, stream>>>(h1_0, h1p + BH, BH / 4);
  cvt_f32_f16<<<512,  256, 0, stream>>>(h2_0, h2p + BH, BH / 4);
  bias_sum<<<16, 256, 0, stream>>>(bih1, bhh1, b1s, 4096);
  bias_sum<<<16, 256, 0, stream>>>(bih2, bhh2, b2s, 4096);
  hipMemcpyAsync(c1b, c1_0, (size_t)BH * 4, hipMemcpyDeviceToDevice, stream);
  hipMemcpyAsync(c2b, c2_0, (size_t)BH * 4, hipMemcpyDeviceToDevice, stream);

  const size_t Oh1 = (size_t)BB * TT * II;
  const size_t Oc1 = Oh1 + BH;
  const size_t Oh2 = Oc1 + BH;
  const size_t Oc2 = Oh2 + BH;

  for (int t = 0; t < TT; ++t) {
    const bool last = (t == TT - 1);
    _Float16* h1r = h1p + (size_t)((t + 1) & 1) * BH;
    _Float16* h1w = h1p + (size_t)(t & 1) * BH;
    _Float16* h2r = h2p + (size_t)((t + 1) & 1) * BH;
    _Float16* h2w = h2p + (size_t)(t & 1) * BH;

    phaseA<<<1040, 256, 0, stream>>>(
        xh + (size_t)t * II, h1r, h2r, wih1h, whh1h, whh2h,
        b1s, c1b, h1w,
        last ? out + Oh1 : nullptr, last ? out + Oc1 : nullptr,
        pbuf, fcwh, fcb,
        (t > 0) ? out + (size_t)(t - 1) * II : nullptr,
        512, 512, 130);

    phaseB<<<1024, 256, 0, stream>>>(
        h1w, wih2h, b2s, pbuf, c2b, h2w,
        last ? out + Oh2 : nullptr, last ? out + Oc2 : nullptr,
        128);
  }

  // final fc: y_{T-1} from h2_{T-1} (slot (T-1)&1 = 1)
  phaseA<<<16, 256, 0, stream>>>(
      nullptr, nullptr, h2p + BH, wih1h, whh1h, whh2h,
      b1s, c1b, nullptr, nullptr, nullptr,
      pbuf, fcwh, fcb,
      out + (size_t)(TT - 1) * II,
      0, 0, 2);

  (void)in_sizes; (void)n_in; (void)out_size; (void)ws_size;
}

// Round 7
// 7781.068 us; speedup vs baseline: 1.4498x; 1.4498x over previous
//
#include <hip/hip_runtime.h>

// ---------------------------------------------------------------------------
// 2-layer LSTM (B=2048, T=64, I=128, H=1024) + per-step fc, MI355X/gfx950.
// Round 4 kernel, 4th submission (r4/r5/r6 benches were infra timeouts):
// r1 schedule (cell1; cell2+fc rider) + PRE-STAGED WEIGHT IMAGES: weights are
// transformed once per call into the exact [kt][idx][8] fp16 stream the
// K-loop stages, so every B global_load_lds is a fully coalesced contiguous
// 1KB/wave read (was 64x 16B at 2KB row stride). Theory: per-CU request-rate
// saturation from strided staging is the ~270TF ceiling (blocks/CU-invariant
// per r3). A-staging (h state) unchanged (cell1 proved ~700TF with it).
// ---------------------------------------------------------------------------

typedef _Float16 f16x8 __attribute__((ext_vector_type(8)));
typedef _Float16 f16x4 __attribute__((ext_vector_type(4)));
typedef float    f32x4 __attribute__((ext_vector_type(4)));

#define DEVI __device__ __forceinline__

constexpr int BB = 2048;
constexpr int TT = 64;
constexpr int II = 128;
constexpr int HH = 1024;
constexpr int BH = BB * HH;

DEVI void gload_lds16(const _Float16* g, _Float16* l) {
  __builtin_amdgcn_global_load_lds(
      (const __attribute__((address_space(1))) void*)g,
      (__attribute__((address_space(3))) void*)l, 16, 0, 0);
}

DEVI float fsig(float x)  { return 1.0f / (1.0f + __expf(-x)); }
DEVI float ftanh(float x) { float e = __expf(2.0f * x); return 1.0f - 2.0f / (e + 1.0f); }

// ---------------------------------------------------------------------------
// GEMM core, 128x128 tile. A from global (two K-segments, row-major, strided).
// B from a PRE-STAGED image: Bst[kt*4096 + idx*8 .. +8] already in LDS order
// ([4][128][8] panel-major per K-step) -> staging loads are contiguous.
// ---------------------------------------------------------------------------
DEVI void gemm_core(f32x4 (&acc)[4][4],
    const _Float16* __restrict__ A0, int lda0,
    const _Float16* __restrict__ A1, int lda1,
    const _Float16* __restrict__ Bst,
    int ktSplit, int ktTotal, int m0,
    _Float16* sA0, _Float16* sA1, _Float16* sB0, _Float16* sB1,
    int tid, int wm, int wn, int lr, int lk)
{
  const _Float16* aS0[2]; const _Float16* aS1[2];
#pragma unroll
  for (int i = 0; i < 2; ++i) {
    int idx = i * 256 + tid;
    int p = idx >> 7;            // k-panel 0..3
    int r = idx & 127;           // tile m-row
    aS0[i] = A0 + (size_t)(m0 + r) * lda0 + p * 8;
    aS1[i] = A1 + (size_t)(m0 + r) * lda1 + p * 8;
  }
  const _Float16* bS = Bst + tid * 8;

  auto stage = [&](_Float16* tA, _Float16* tB, int kt) {
    bool s0 = kt < ktSplit;
    int ko = (s0 ? kt : kt - ktSplit) * 32;
#pragma unroll
    for (int i = 0; i < 2; ++i)
      gload_lds16((s0 ? aS0[i] : aS1[i]) + ko, tA + i * 2048 + tid * 8);
    const _Float16* bp = bS + (size_t)kt * 4096;
#pragma unroll
    for (int i = 0; i < 2; ++i)
      gload_lds16(bp + i * 2048, tB + i * 2048 + tid * 8);
  };

  const int aOff = lk * 1024 + (wm * 64 + lr) * 8;
  const int bOff = lk * 1024 + (wn * 64 + lr) * 8;

  auto compute = [&](const _Float16* tA, const _Float16* tB) {
    f16x8 av[4], bv[4];
#pragma unroll
    for (int q = 0; q < 4; ++q) av[q] = *(const f16x8*)(tA + aOff + q * 128);
#pragma unroll
    for (int q = 0; q < 4; ++q) bv[q] = *(const f16x8*)(tB + bOff + q * 128);
#pragma unroll
    for (int i = 0; i < 4; ++i)
#pragma unroll
      for (int j = 0; j < 4; ++j)
        acc[i][j] = __builtin_amdgcn_mfma_f32_16x16x32_f16(av[i], bv[j], acc[i][j], 0, 0, 0);
  };

  stage(sA0, sB0, 0);
  __syncthreads();
  for (int kt = 0; kt < ktTotal; kt += 2) {          // ktTotal always even
    if (kt + 1 < ktTotal) stage(sA1, sB1, kt + 1);
    compute(sA0, sB0);
    __syncthreads();
    if (kt + 2 < ktTotal) stage(sA0, sB0, kt + 2);
    compute(sA1, sB1);
    __syncthreads();
  }
}

// ---------------------------------------------------------------------------
// blocks [0, ncell): LSTM cell tiles (gate-fused epilogue).
// blocks [ncell, ...): fc GEMM for the PREVIOUS step's h2 (independent).
// Cell blocks get a homogeneous XCD swizzle (grid8 = ncell/8).
// ---------------------------------------------------------------------------
__global__ __launch_bounds__(256)
void lstm_gemm(
    const _Float16* __restrict__ A0, int lda0,   // cell A seg0
    const _Float16* __restrict__ A1, int lda1,   // cell A seg1
    const _Float16* __restrict__ BstCell,        // staged cell weights
    int ktSplit, int ktTotal,
    const float* __restrict__ biasCell,          // [4H] = b_ih + b_hh
    float* __restrict__ cbuf,                    // [B,H] fp32 cell state
    _Float16* __restrict__ hout,                 // [B,H] fp16 new hidden
    float* __restrict__ hF32, float* __restrict__ cF32,  // last step only
    const _Float16* __restrict__ fcA,            // fc: h2 of previous step
    const _Float16* __restrict__ BstFc,          // staged fc weights
    const float* __restrict__ fcBias,
    float* __restrict__ yout,                    // d_out + t_prev*II (null->skip)
    int ncell, int grid8)
{
  __shared__ __align__(16) _Float16 sA[2][4096];
  __shared__ __align__(16) _Float16 sB[2][4096];

  const int tid  = threadIdx.x;
  const int lane = tid & 63;
  const int wid  = tid >> 6;
  const int wm = wid >> 1, wn = wid & 1;
  const int lr = lane & 15, lk = lane >> 4;

  const f32x4 vzero = {0.f, 0.f, 0.f, 0.f};
  f32x4 acc[4][4];
#pragma unroll
  for (int i = 0; i < 4; ++i)
#pragma unroll
    for (int j = 0; j < 4; ++j) acc[i][j] = vzero;

  if ((int)blockIdx.x < ncell) {
    // -------------------- LSTM cell tile --------------------
    const int swz = ((int)blockIdx.x % 8) * grid8 + (int)blockIdx.x / 8;
    const int nt = swz >> 4;           // panel-major: each XCD owns whole panels
    const int mt = swz & 15;
    const int m0 = mt * 128, u0 = nt * 32;
    gemm_core(acc, A0, lda0, A1, lda1,
              BstCell + (size_t)nt * ktTotal * 4096,
              ktSplit, ktTotal, m0,
              sA[0], sA[1], sB[0], sB[1], tid, wm, wn, lr, lk);

    const int u = u0 + wn * 16 + lr;
    const float bi = biasCell[u];
    const float bf = biasCell[HH + u];
    const float bg = biasCell[2 * HH + u];
    const float bo = biasCell[3 * HH + u];
#pragma unroll
    for (int mf = 0; mf < 4; ++mf)
#pragma unroll
      for (int rg = 0; rg < 4; ++rg) {
        const int m = m0 + wm * 64 + mf * 16 + lk * 4 + rg;
        const size_t off = (size_t)m * HH + u;
        float iv = fsig (acc[mf][0][rg] + bi);
        float fv = fsig (acc[mf][1][rg] + bf);
        float gv = ftanh(acc[mf][2][rg] + bg);
        float ov = fsig (acc[mf][3][rg] + bo);
        float cn = fv * cbuf[off] + iv * gv;
        float hn = ov * ftanh(cn);
        cbuf[off] = cn;
        hout[off] = (_Float16)hn;
        if (hF32) { hF32[off] = hn; cF32[off] = cn; }
      }
  } else {
    // -------------------- fc tile (previous step's h2) --------------------
    if (yout == nullptr) return;
    const int m0 = ((int)blockIdx.x - ncell) * 128;
    gemm_core(acc, fcA, HH, fcA, HH, BstFc,
              32, 32, m0,
              sA[0], sA[1], sB[0], sB[1], tid, wm, wn, lr, lk);
#pragma unroll
    for (int mf = 0; mf < 4; ++mf)
#pragma unroll
      for (int fn = 0; fn < 4; ++fn) {
        const int col = wn * 64 + fn * 16 + lr;
        const float bb = fcBias[col];
#pragma unroll
        for (int rg = 0; rg < 4; ++rg) {
          const int m = m0 + wm * 64 + mf * 16 + lk * 4 + rg;
          yout[(size_t)m * (TT * II) + col] = acc[mf][fn][rg] + bb;
        }
      }
  }
}

// ---------------------------------------------------------------------------
// Prologue: build the staged weight image.
// Block = (nt, kt). Output element (idx = i*256+tid, e) with p=idx>>7,
// r=idx&127 gets W_seg[brow(r)][ko + p*8 + e], brow gate-mapped iff gates.
// Writes are fully coalesced (consecutive tid -> consecutive 16B).
// ---------------------------------------------------------------------------
__global__ void stage_w(const float* __restrict__ seg0, int ld0,
                        const float* __restrict__ seg1, int ld1,
                        int ktSplit, int ktTotal, int gates, int nPan,
                        _Float16* __restrict__ outp)
{
  const int blk = blockIdx.x;               // nt*ktTotal + kt
  const int nt = blk / ktTotal, kt = blk % ktTotal;
  const float* src; int ld, ko;
  if (kt < ktSplit) { src = seg0; ld = ld0; ko = kt * 32; }
  else             { src = seg1; ld = ld1; ko = (kt - ktSplit) * 32; }
  const int tid = threadIdx.x;
  (void)nPan;
#pragma unroll
  for (int i = 0; i < 2; ++i) {
    int idx = i * 256 + tid;
    int p = idx >> 7, r = idx & 127;
    int br = gates ? (((r >> 4) & 3) * HH + nt * 32 + ((r >> 6) << 4) + (r & 15))
                   : r;
    const float* s = src + (size_t)br * ld + ko + p * 8;
    f16x8 h;
#pragma unroll
    for (int e = 0; e < 8; ++e) h[e] = (_Float16)s[e];
    *(f16x8*)(outp + ((size_t)blk * 512 + idx) * 8) = h;
  }
}

__global__ void cvt_f32_f16(const float* __restrict__ in,
                            _Float16* __restrict__ out, int n4) {
  int i  = blockIdx.x * blockDim.x + threadIdx.x;
  int st = gridDim.x * blockDim.x;
  for (; i < n4; i += st) {
    float4 v = ((const float4*)in)[i];
    f16x4 h;
    h[0] = (_Float16)v.x; h[1] = (_Float16)v.y;
    h[2] = (_Float16)v.z; h[3] = (_Float16)v.w;
    ((f16x4*)out)[i] = h;
  }
}

__global__ void bias_sum(const float* __restrict__ a, const float* __restrict__ b,
                         float* __restrict__ o, int n) {
  int i = blockIdx.x * blockDim.x + threadIdx.x;
  if (i < n) o[i] = a[i] + b[i];
}

// ---------------------------------------------------------------------------
extern "C" void kernel_launch(void* const* d_in, const int* in_sizes, int n_in,
                              void* d_out, int out_size, void* d_ws, size_t ws_size,
                              hipStream_t stream) {
  const float* x    = (const float*)d_in[0];
  const float* h1_0 = (const float*)d_in[1];
  const float* c1_0 = (const float*)d_in[2];
  const float* h2_0 = (const float*)d_in[3];
  const float* c2_0 = (const float*)d_in[4];
  const float* wih1 = (const float*)d_in[5];
  const float* whh1 = (const float*)d_in[6];
  const float* bih1 = (const float*)d_in[7];
  const float* bhh1 = (const float*)d_in[8];
  const float* wih2 = (const float*)d_in[9];
  const float* whh2 = (const float*)d_in[10];
  const float* bih2 = (const float*)d_in[11];
  const float* bhh2 = (const float*)d_in[12];
  const float* fcw  = (const float*)d_in[13];
  const float* fcb  = (const float*)d_in[14];
  float* out = (float*)d_out;

  // ---- workspace carve-out (~92 MB) ----
  char* p = (char*)d_ws;
  auto take = [&](size_t bytes) -> void* {
    void* r = (void*)p;
    p += (bytes + 511) & ~(size_t)511;
    return r;
  };
  _Float16* xh   = (_Float16*)take((size_t)BB * TT * II * 2);          // 32 MB
  _Float16* st1  = (_Float16*)take((size_t)32 * 36 * 4096 * 2);        // 9.4 MB
  _Float16* st2  = (_Float16*)take((size_t)32 * 64 * 4096 * 2);        // 16.8 MB
  _Float16* stfc = (_Float16*)take((size_t)1  * 32 * 4096 * 2);        // 0.26 MB
  float*    b1s  = (float*)take(4096 * 4);
  float*    b2s  = (float*)take(4096 * 4);
  _Float16* h1p  = (_Float16*)take((size_t)2 * BH * 2);
  _Float16* h2p  = (_Float16*)take((size_t)2 * BH * 2);
  float*    c1b  = (float*)take((size_t)BH * 4);
  float*    c2b  = (float*)take((size_t)BH * 4);

  // ---- prologue ----
  cvt_f32_f16<<<1024, 256, 0, stream>>>(x, xh, BB * TT * II / 4);
  cvt_f32_f16<<<512,  256, 0, stream>>>(h1_0, h1p + BH, BH / 4);   // slot 1
  cvt_f32_f16<<<512,  256, 0, stream>>>(h2_0, h2p + BH, BH / 4);   // slot 1
  bias_sum<<<16, 256, 0, stream>>>(bih1, bhh1, b1s, 4096);
  bias_sum<<<16, 256, 0, stream>>>(bih2, bhh2, b2s, 4096);
  stage_w<<<32 * 36, 256, 0, stream>>>(wih1, II, whh1, HH, 4, 36, 1, 32, st1);
  stage_w<<<32 * 64, 256, 0, stream>>>(wih2, HH, whh2, HH, 32, 64, 1, 32, st2);
  stage_w<<<32,      256, 0, stream>>>(fcw,  HH, fcw,  HH, 32, 32, 0, 1,  stfc);
  hipMemcpyAsync(c1b, c1_0, (size_t)BH * 4, hipMemcpyDeviceToDevice, stream);
  hipMemcpyAsync(c2b, c2_0, (size_t)BH * 4, hipMemcpyDeviceToDevice, stream);

  const size_t Oh1 = (size_t)BB * TT * II;
  const size_t Oc1 = Oh1 + BH;
  const size_t Oh2 = Oc1 + BH;
  const size_t Oc2 = Oh2 + BH;

  for (int t = 0; t < TT; ++t) {
    const bool last = (t == TT - 1);
    _Float16* h1r = h1p + (size_t)((t + 1) & 1) * BH;
    _Float16* h1w = h1p + (size_t)(t & 1) * BH;
    _Float16* h2r = h2p + (size_t)((t + 1) & 1) * BH;
    _Float16* h2w = h2p + (size_t)(t & 1) * BH;

    // cell1: gates = x_t@Wih1^T + h1_{t-1}@Whh1^T   (K = 128 + 1024)
    lstm_gemm<<<512, 256, 0, stream>>>(
        xh + (size_t)t * II, TT * II, h1r, HH, st1,
        4, 36, b1s, c1b, h1w,
        last ? out + Oh1 : nullptr, last ? out + Oc1 : nullptr,
        nullptr, nullptr, nullptr, nullptr, 512, 64);

    // cell2 (+ fc of step t-1 riding on 16 extra blocks)
    lstm_gemm<<<528, 256, 0, stream>>>(
        h1w, HH, h2r, HH, st2,
        32, 64, b2s, c2b, h2w,
        last ? out + Oh2 : nullptr, last ? out + Oc2 : nullptr,
        h2r, stfc, fcb,
        (t > 0) ? out + (size_t)(t - 1) * II : nullptr, 512, 64);
  }

  // final fc: y_{T-1} from h2_{T-1} (slot (T-1)&1 = 1)
  lstm_gemm<<<16, 256, 0, stream>>>(
      nullptr, 0, nullptr, 0, nullptr,
      0, 0, nullptr, nullptr, nullptr, nullptr, nullptr,
      h2p + BH, stfc, fcb, out + (size_t)(TT - 1) * II, 0, 2);

  (void)in_sizes; (void)n_in; (void)out_size; (void)ws_size;
}